// Round 4
// baseline (548.552 us; speedup 1.0000x reference)
//
#include <hip/hip_runtime.h>
#include <math.h>

#define NNODES 50000
#define NEDGES 400000
#define HEADS 4
#define NPAD 50048       // 391 * 128
#define NSCAN_BLK 196    // ceil(NNODES/256)
#define XROW 523
#define KP0 544
#define TPR 68           // threads per row in conv_x_v2 (544/8)

typedef __attribute__((ext_vector_type(8))) short bf16x8;
typedef __attribute__((ext_vector_type(4))) float f32x4;
typedef __attribute__((ext_vector_type(4))) unsigned short u16x4;
typedef __attribute__((ext_vector_type(8))) unsigned short u16x8;

__device__ inline unsigned short f2bf(float f) {
    union { float f; unsigned u; } t; t.f = f;
    unsigned u = t.u;
    u += 0x7fffu + ((u >> 16) & 1u);
    return (unsigned short)(u >> 16);
}
__device__ inline float bf2f(unsigned short s) {
    union { unsigned u; float f; } t; t.u = ((unsigned)s) << 16;
    return t.f;
}

// ---------------- CSR build (edge_index is constant across layers) -----------
__global__ void count_deg(const int* __restrict__ dst, int* __restrict__ cnt) {
    int e = blockIdx.x * blockDim.x + threadIdx.x;
    if (e < NEDGES) atomicAdd(&cnt[dst[e]], 1);
}

// ---- parallel exclusive scan over cnt[NNODES]: 3 tiny kernels ----
__global__ __launch_bounds__(256)
void scan_p1(const int* __restrict__ cnt, int* __restrict__ bsum) {
    int i = blockIdx.x * 256 + threadIdx.x;
    int v = (i < NNODES) ? cnt[i] : 0;
#pragma unroll
    for (int off = 1; off < 64; off <<= 1) v += __shfl_xor(v, off);
    __shared__ int ws[4];
    if ((threadIdx.x & 63) == 0) ws[threadIdx.x >> 6] = v;
    __syncthreads();
    if (threadIdx.x == 0) bsum[blockIdx.x] = ws[0] + ws[1] + ws[2] + ws[3];
}

__global__ __launch_bounds__(256)
void scan_p2(const int* __restrict__ bsum, int* __restrict__ boff,
             int* __restrict__ rowptr) {
    int tid = threadIdx.x;
    int v = (tid < NSCAN_BLK) ? bsum[tid] : 0;
    int orig = v;
    int lane = tid & 63, wid = tid >> 6;
#pragma unroll
    for (int off = 1; off < 64; off <<= 1) {
        int t = __shfl_up(v, off);
        if (lane >= off) v += t;
    }
    __shared__ int ws[4];
    if (lane == 63) ws[wid] = v;
    __syncthreads();
    int add = 0;
    for (int w = 0; w < wid; ++w) add += ws[w];
    v += add;
    if (tid < NSCAN_BLK) boff[tid] = v - orig;   // exclusive block offset
    if (tid == 255) rowptr[NNODES] = v;          // grand total
}

__global__ __launch_bounds__(256)
void scan_p3(const int* __restrict__ cnt, const int* __restrict__ boff,
             int* __restrict__ rowptr, int* __restrict__ cursor) {
    int i = blockIdx.x * 256 + threadIdx.x;
    int v = (i < NNODES) ? cnt[i] : 0;
    int orig = v;
    int lane = threadIdx.x & 63, wid = threadIdx.x >> 6;
#pragma unroll
    for (int off = 1; off < 64; off <<= 1) {
        int t = __shfl_up(v, off);
        if (lane >= off) v += t;
    }
    __shared__ int ws[4];
    if (lane == 63) ws[wid] = v;
    __syncthreads();
    int add = boff[blockIdx.x];
    for (int w = 0; w < wid; ++w) add += ws[w];
    v += add;
    if (i < NNODES) {
        int ex = v - orig;
        rowptr[i] = ex;
        cursor[i] = ex;
    }
}

__global__ void fill_csr(const int* __restrict__ src, const int* __restrict__ dst,
                         int* __restrict__ cursor, int* __restrict__ srcs) {
    int e = blockIdx.x * blockDim.x + threadIdx.x;
    if (e >= NEDGES) return;
    int p = atomicAdd(&cursor[dst[e]], 1);
    srcs[p] = src[e];
}

// X fp32 [N][523] -> XB bf16 [NPAD][544] (layer 0 only).
// 8 outputs/thread: 32B coalesced read, one 16B vector store.
__global__ __launch_bounds__(256)
void conv_x_v2(const float* __restrict__ X, unsigned short* __restrict__ XB) {
    unsigned t = blockIdx.x * 256 + threadIdx.x;
    unsigned r = t / TPR;
    unsigned c0 = (t % TPR) * 8;
    if (r >= NPAD) return;
    u16x8 o;
    if (r < NNODES) {
        const float* xp = X + (size_t)r * XROW + c0;
        if (c0 + 8 <= XROW) {
#pragma unroll
            for (int q = 0; q < 8; ++q) o[q] = f2bf(xp[q]);
        } else {
#pragma unroll
            for (int q = 0; q < 8; ++q)
                o[q] = (c0 + q < XROW) ? f2bf(xp[q]) : (unsigned short)0;
        }
    } else {
#pragma unroll
        for (int q = 0; q < 8; ++q) o[q] = 0;
    }
    *(u16x8*)(XB + (size_t)r * KP0 + c0) = o;
}

// W fp32 [din][dout] -> Wt bf16 [dout][Kp]
__global__ void conv_wt(const float* __restrict__ W, unsigned short* __restrict__ Wt,
                        int din, int dout, int Kp) {
    int k = blockIdx.x * blockDim.x + threadIdx.x;
    int mcol = blockIdx.y;
    if (k >= Kp) return;
    unsigned short v = 0;
    if (k < din) v = f2bf(W[(size_t)k * dout + mcol]);
    Wt[(size_t)mcol * Kp + k] = v;
}

// ---- MFMA GEMM: C[n][m] = A[n][k] * Bt[m][k]^T, bf16 in / bf16 out ----
// Fused attention-scalar epilogue: asrc[n,h] = Wx[n,head h]·a[:HD],
// adst[n,h] = Wx[n,head h]·a[HD:]. Each wave's 64-col window lies within one
// head (HD=64 or 128, windows 64-aligned). dout=256: one wave per (row,h) ->
// plain store. dout=512: two waves (wn=0,64) share a head -> atomicAdd
// (asrc/adst pre-zeroed).
template <int HD, bool ATOMIC>
__global__ __launch_bounds__(256)
void gemm_mfma(const unsigned short* __restrict__ A, const unsigned short* __restrict__ Bt,
               unsigned short* __restrict__ C, const float* __restrict__ a_att,
               float* __restrict__ asrc, float* __restrict__ adst, int Kp, int m) {
    __shared__ unsigned short sA[128 * 32];
    __shared__ unsigned short sB[128 * 32];
    int tid = threadIdx.x;
    int lane = tid & 63, wave = tid >> 6;
    int wm = (wave & 1) * 64, wn = (wave >> 1) * 64;
    int rowbase = blockIdx.y * 128;
    int colbase = blockIdx.x * 128;

    f32x4 acc[4][4] = {};

    const unsigned short* Ab = A + (size_t)rowbase * Kp;
    const unsigned short* Bb = Bt + (size_t)colbase * Kp;

    int c0 = tid, c1 = tid + 256;
    int r0 = c0 >> 2, o0 = (c0 & 3) << 3;
    int r1 = c1 >> 2, o1 = (c1 & 3) << 3;

    int arow = wm + (lane & 15);
    int brow = wn + (lane & 15);
    int koff = (lane >> 4) * 8;

    for (int k0 = 0; k0 < Kp; k0 += 32) {
        __builtin_amdgcn_global_load_lds(
            (const __attribute__((address_space(1))) void*)(Ab + (size_t)r0 * Kp + k0 + o0),
            (__attribute__((address_space(3))) void*)(sA + c0 * 8), 16, 0, 0);
        __builtin_amdgcn_global_load_lds(
            (const __attribute__((address_space(1))) void*)(Ab + (size_t)r1 * Kp + k0 + o1),
            (__attribute__((address_space(3))) void*)(sA + c1 * 8), 16, 0, 0);
        __builtin_amdgcn_global_load_lds(
            (const __attribute__((address_space(1))) void*)(Bb + (size_t)r0 * Kp + k0 + o0),
            (__attribute__((address_space(3))) void*)(sB + c0 * 8), 16, 0, 0);
        __builtin_amdgcn_global_load_lds(
            (const __attribute__((address_space(1))) void*)(Bb + (size_t)r1 * Kp + k0 + o1),
            (__attribute__((address_space(3))) void*)(sB + c1 * 8), 16, 0, 0);
        __syncthreads();

        bf16x8 af[4], bfr[4];
#pragma unroll
        for (int i = 0; i < 4; ++i)
            af[i] = *(const bf16x8*)(sA + (arow + i * 16) * 32 + koff);
#pragma unroll
        for (int i = 0; i < 4; ++i)
            bfr[i] = *(const bf16x8*)(sB + (brow + i * 16) * 32 + koff);
#pragma unroll
        for (int mi = 0; mi < 4; ++mi)
#pragma unroll
            for (int ni = 0; ni < 4; ++ni)
                acc[mi][ni] = __builtin_amdgcn_mfma_f32_16x16x32_bf16(
                    af[mi], bfr[ni], acc[mi][ni], 0, 0, 0);
        __syncthreads();
    }

    int crow0 = rowbase + wm + (lane >> 4) * 4;
    int ccol0 = colbase + wn + (lane & 15);
#pragma unroll
    for (int mi = 0; mi < 4; ++mi) {
#pragma unroll
        for (int r = 0; r < 4; ++r) {
            int row = crow0 + mi * 16 + r;
            if (row < NNODES) {
#pragma unroll
                for (int ni = 0; ni < 4; ++ni)
                    C[(size_t)row * m + ccol0 + ni * 16] = f2bf(acc[mi][ni][r]);
            }
        }
    }

    // ---- fused attention scalars ----
    int h = ccol0 / HD;            // uniform per wave (window within one head)
    float ca_s[4], ca_d[4];
#pragma unroll
    for (int ni = 0; ni < 4; ++ni) {
        int dl = (ccol0 % HD) + ni * 16;   // local dim within head
        ca_s[ni] = a_att[dl];
        ca_d[ni] = a_att[HD + dl];
    }
#pragma unroll
    for (int mi = 0; mi < 4; ++mi) {
#pragma unroll
        for (int r = 0; r < 4; ++r) {
            float s1 = 0.f, s2 = 0.f;
#pragma unroll
            for (int ni = 0; ni < 4; ++ni) {
                float v = acc[mi][ni][r];
                s1 = fmaf(v, ca_s[ni], s1);
                s2 = fmaf(v, ca_d[ni], s2);
            }
#pragma unroll
            for (int off = 1; off < 16; off <<= 1) {
                s1 += __shfl_xor(s1, off);
                s2 += __shfl_xor(s2, off);
            }
            int row = crow0 + mi * 16 + r;
            if ((lane & 15) == 0 && row < NNODES) {
                if constexpr (ATOMIC) {
                    atomicAdd(&asrc[row * HEADS + h], s1);
                    atomicAdd(&adst[row * HEADS + h], s2);
                } else {
                    asrc[row * HEADS + h] = s1;
                    adst[row * HEADS + h] = s2;
                }
            }
        }
    }
}

// -------------- fused gather-aggregate + softmax + ELU + LayerNorm -----------
// One wave per node. Lane owns PER contiguous outputs; head h = lane>>4.
// Denominator folded: out = (sum_e exp_e * Wx_src) / (sum_e exp_e + 1e-8).
// dsum accumulated lane-locally (own edge's ex), reduced once at the end.
template <int DOUT, bool OUT_BF>
__global__ __launch_bounds__(256)
void aggregate_wave(const int* __restrict__ rowptr, const int* __restrict__ srcs,
                    const float* __restrict__ asrc, const float* __restrict__ adst,
                    const unsigned short* __restrict__ WxB,
                    const float* __restrict__ g, const float* __restrict__ b,
                    void* __restrict__ outp) {
    constexpr int PER = DOUT / 64;     // 4 (DOUT=256) or 8 (DOUT=512)
    int wid = threadIdx.x >> 6, lane = threadIdx.x & 63;
    int node = blockIdx.x * 4 + wid;
    if (node >= NNODES) return;

    int h = lane >> 4;                 // head for this lane's output slice
    int li = lane & 15;
    int hb = lane & 48;                // shfl base for this head group
    int beg = rowptr[node], end = rowptr[node + 1];
    float adh = adst[node * HEADS + h];

    const unsigned short* wb = WxB + lane * PER;

    float acc[PER];
#pragma unroll
    for (int q = 0; q < PER; ++q) acc[q] = 0.f;
    float dloc = 0.f;

    typedef __attribute__((ext_vector_type(PER))) unsigned short uvec;

    for (int cb = beg; cb < end; cb += 16) {
        int cnt = min(16, end - cb);
        int s = 0;
        float ex = 0.f;
        if (li < cnt) {
            s = srcs[cb + li];
            float e = asrc[s * HEADS + h] + adh;
            e = e > 0.f ? e : 0.2f * e;
            ex = __expf(e);
        }
        dloc += ex;
        int i = 0;
        for (; i + 4 <= cnt; i += 4) {
            int s0 = __builtin_amdgcn_readlane(s, i);
            int s1 = __builtin_amdgcn_readlane(s, i + 1);
            int s2 = __builtin_amdgcn_readlane(s, i + 2);
            int s3 = __builtin_amdgcn_readlane(s, i + 3);
            uvec v0 = *(const uvec*)(wb + (size_t)s0 * DOUT);
            uvec v1 = *(const uvec*)(wb + (size_t)s1 * DOUT);
            uvec v2 = *(const uvec*)(wb + (size_t)s2 * DOUT);
            uvec v3 = *(const uvec*)(wb + (size_t)s3 * DOUT);
            float w0 = __shfl(ex, hb | i);
            float w1 = __shfl(ex, hb | (i + 1));
            float w2 = __shfl(ex, hb | (i + 2));
            float w3 = __shfl(ex, hb | (i + 3));
#pragma unroll
            for (int q = 0; q < PER; ++q) {
                float t0 = fmaf(w0, bf2f(v0[q]), acc[q]);
                float t1 = fmaf(w1, bf2f(v1[q]), t0);
                float t2 = fmaf(w2, bf2f(v2[q]), t1);
                acc[q] = fmaf(w3, bf2f(v3[q]), t2);
            }
        }
        for (; i < cnt; ++i) {
            int si = __builtin_amdgcn_readlane(s, i);
            uvec v = *(const uvec*)(wb + (size_t)si * DOUT);
            float w = __shfl(ex, hb | i);
#pragma unroll
            for (int q = 0; q < PER; ++q)
                acc[q] = fmaf(w, bf2f(v[q]), acc[q]);
        }
    }

    // reduce per-head denominator across the 16-lane group
    float dsum = dloc;
#pragma unroll
    for (int off = 1; off < 16; off <<= 1) dsum += __shfl_xor(dsum, off);

    float rd = 1.f / (dsum + 1e-8f);
    float vals[PER];
    float lsum = 0.f, lsq = 0.f;
#pragma unroll
    for (int q = 0; q < PER; ++q) {
        float v = acc[q] * rd;
        v = v > 0.f ? v : __expf(v) - 1.f;   // ELU
        vals[q] = v;
        lsum += v;
        lsq = fmaf(v, v, lsq);
    }
#pragma unroll
    for (int off = 1; off < 64; off <<= 1) {
        lsum += __shfl_xor(lsum, off);
        lsq += __shfl_xor(lsq, off);
    }
    float mean = lsum * (1.0f / DOUT);
    float var = lsq * (1.0f / DOUT) - mean * mean;
    float rstd = rsqrtf(var + 1e-5f);

    int j = lane * PER;
    f32x4 g0 = *(const f32x4*)(g + j);
    f32x4 b0 = *(const f32x4*)(b + j);
    float r[PER];
#pragma unroll
    for (int q = 0; q < 4; ++q) r[q] = (vals[q] - mean) * rstd * g0[q] + b0[q];
    if constexpr (PER == 8) {
        f32x4 g1 = *(const f32x4*)(g + j + 4);
        f32x4 b1 = *(const f32x4*)(b + j + 4);
#pragma unroll
        for (int q = 0; q < 4; ++q)
            r[q + 4] = (vals[q + 4] - mean) * rstd * g1[q] + b1[q];
    }

    if constexpr (OUT_BF) {
        unsigned short* o = (unsigned short*)outp + (size_t)node * DOUT + j;
        u16x4 o0;
#pragma unroll
        for (int q = 0; q < 4; ++q) o0[q] = f2bf(r[q]);
        *(u16x4*)o = o0;
        if constexpr (PER == 8) {
            u16x4 o1;
#pragma unroll
            for (int q = 0; q < 4; ++q) o1[q] = f2bf(r[q + 4]);
            *(u16x4*)(o + 4) = o1;
        }
    } else {
        float* o = (float*)outp + (size_t)node * DOUT + j;
        f32x4 v0 = {r[0], r[1], r[2], r[3]};
        *(f32x4*)o = v0;
        if constexpr (PER == 8) {
            f32x4 v1 = {r[4], r[5], r[6], r[7]};
            *(f32x4*)(o + 4) = v1;
        }
    }
}

extern "C" void kernel_launch(void* const* d_in, const int* in_sizes, int n_in,
                              void* d_out, int out_size, void* d_ws, size_t ws_size,
                              hipStream_t stream) {
    const float* x0 = (const float*)d_in[0];
    const int* ei = (const int*)d_in[1];
    const int* src = ei;
    const int* dst = ei + NEDGES;
    const float* W[3]  = {(const float*)d_in[2], (const float*)d_in[6],  (const float*)d_in[10]};
    const float* a[3]  = {(const float*)d_in[3], (const float*)d_in[7],  (const float*)d_in[11]};
    const float* g[3]  = {(const float*)d_in[4], (const float*)d_in[8],  (const float*)d_in[12]};
    const float* bb[3] = {(const float*)d_in[5], (const float*)d_in[9],  (const float*)d_in[13]};

    char* p = (char*)d_ws;
    auto carve = [&](size_t bytes) {
        char* r = p;
        p += (bytes + 255) & ~(size_t)255;
        return r;
    };
    unsigned short* XB   = (unsigned short*)carve((size_t)NPAD * 544 * 2);
    unsigned short* WxB  = (unsigned short*)carve((size_t)NNODES * 512 * 2);
    unsigned short* Wt   = (unsigned short*)carve((size_t)512 * 544 * 2);
    float* ASRC  = (float*)carve((size_t)NNODES * HEADS * 4);
    float* ADST  = (float*)carve((size_t)NNODES * HEADS * 4);
    int* CNT  = (int*)carve((size_t)NNODES * 4);
    int* ROWP = (int*)carve((size_t)(NNODES + 1) * 4);
    int* CURS = (int*)carve((size_t)NNODES * 4);
    int* SRCS = (int*)carve((size_t)NEDGES * 4);
    int* BSUM = (int*)carve(256 * 4);
    int* BOFF = (int*)carve(256 * 4);

    hipMemsetAsync(CNT, 0, (size_t)NNODES * 4, stream);
    count_deg<<<(NEDGES + 255) / 256, 256, 0, stream>>>(dst, CNT);
    scan_p1<<<NSCAN_BLK, 256, 0, stream>>>(CNT, BSUM);
    scan_p2<<<1, 256, 0, stream>>>(BSUM, BOFF, ROWP);
    scan_p3<<<NSCAN_BLK, 256, 0, stream>>>(CNT, BOFF, ROWP, CURS);
    fill_csr<<<(NEDGES + 255) / 256, 256, 0, stream>>>(src, dst, CURS, SRCS);

    const int dims[4] = {523, 256, 256, 512};
    const int Kps[3] = {544, 256, 256};
    for (int li = 0; li < 3; ++li) {
        int din = dims[li], dout = dims[li + 1];
        int Kp = Kps[li];

        if (li == 0) {
            conv_x_v2<<<(NPAD * TPR) / 256, 256, 0, stream>>>(x0, XB);
        }
        conv_wt<<<dim3((Kp + 255) / 256, dout), 256, 0, stream>>>(W[li], Wt, din, dout, Kp);

        if (li == 2) {
            // zero asrc+adst (contiguous carves) for atomic accumulation
            hipMemsetAsync(ASRC, 0, (size_t)NNODES * HEADS * 4 * 2, stream);
            gemm_mfma<128, true><<<dim3(dout / 128, NPAD / 128), 256, 0, stream>>>(
                XB, Wt, WxB, a[li], ASRC, ADST, Kp, dout);
        } else {
            gemm_mfma<64, false><<<dim3(dout / 128, NPAD / 128), 256, 0, stream>>>(
                XB, Wt, WxB, a[li], ASRC, ADST, Kp, dout);
        }

        if (li == 2) {
            aggregate_wave<512, false><<<(NNODES + 3) / 4, 256, 0, stream>>>(
                ROWP, SRCS, ASRC, ADST, WxB, g[li], bb[li], d_out);
        } else {
            aggregate_wave<256, true><<<(NNODES + 3) / 4, 256, 0, stream>>>(
                ROWP, SRCS, ASRC, ADST, WxB, g[li], bb[li], (void*)XB);
            hipMemsetAsync(XB + (size_t)NNODES * 256, 0, (size_t)(NPAD - NNODES) * 256 * 2, stream);
        }
    }
}

// Round 5
// 514.226 us; speedup vs baseline: 1.0668x; 1.0668x over previous
//
#include <hip/hip_runtime.h>
#include <math.h>

#define NNODES 50000
#define NEDGES 400000
#define HEADS 4
#define NPAD 50048       // 391 * 128
#define NSCAN_BLK 196    // ceil(NNODES/256)
#define XROW 523
#define KP0 576          // K padded to multiple of 64 for BK=64 GEMM
#define TPR 72           // threads per row in conv_x_v2 (576/8)

typedef __attribute__((ext_vector_type(8))) short bf16x8;
typedef __attribute__((ext_vector_type(4))) float f32x4;
typedef __attribute__((ext_vector_type(4))) unsigned short u16x4;
typedef __attribute__((ext_vector_type(8))) unsigned short u16x8;

__device__ inline unsigned short f2bf(float f) {
    union { float f; unsigned u; } t; t.f = f;
    unsigned u = t.u;
    u += 0x7fffu + ((u >> 16) & 1u);
    return (unsigned short)(u >> 16);
}
__device__ inline float bf2f(unsigned short s) {
    union { unsigned u; float f; } t; t.u = ((unsigned)s) << 16;
    return t.f;
}

// ---------------- CSR build (edge_index is constant across layers) -----------
__global__ void count_deg(const int* __restrict__ dst, int* __restrict__ cnt) {
    int e = blockIdx.x * blockDim.x + threadIdx.x;
    if (e < NEDGES) atomicAdd(&cnt[dst[e]], 1);
}

// ---- parallel exclusive scan over cnt[NNODES]: 3 tiny kernels ----
__global__ __launch_bounds__(256)
void scan_p1(const int* __restrict__ cnt, int* __restrict__ bsum) {
    int i = blockIdx.x * 256 + threadIdx.x;
    int v = (i < NNODES) ? cnt[i] : 0;
#pragma unroll
    for (int off = 1; off < 64; off <<= 1) v += __shfl_xor(v, off);
    __shared__ int ws[4];
    if ((threadIdx.x & 63) == 0) ws[threadIdx.x >> 6] = v;
    __syncthreads();
    if (threadIdx.x == 0) bsum[blockIdx.x] = ws[0] + ws[1] + ws[2] + ws[3];
}

__global__ __launch_bounds__(256)
void scan_p2(const int* __restrict__ bsum, int* __restrict__ boff,
             int* __restrict__ rowptr) {
    int tid = threadIdx.x;
    int v = (tid < NSCAN_BLK) ? bsum[tid] : 0;
    int orig = v;
    int lane = tid & 63, wid = tid >> 6;
#pragma unroll
    for (int off = 1; off < 64; off <<= 1) {
        int t = __shfl_up(v, off);
        if (lane >= off) v += t;
    }
    __shared__ int ws[4];
    if (lane == 63) ws[wid] = v;
    __syncthreads();
    int add = 0;
    for (int w = 0; w < wid; ++w) add += ws[w];
    v += add;
    if (tid < NSCAN_BLK) boff[tid] = v - orig;   // exclusive block offset
    if (tid == 255) rowptr[NNODES] = v;          // grand total
}

__global__ __launch_bounds__(256)
void scan_p3(const int* __restrict__ cnt, const int* __restrict__ boff,
             int* __restrict__ rowptr, int* __restrict__ cursor) {
    int i = blockIdx.x * 256 + threadIdx.x;
    int v = (i < NNODES) ? cnt[i] : 0;
    int orig = v;
    int lane = threadIdx.x & 63, wid = threadIdx.x >> 6;
#pragma unroll
    for (int off = 1; off < 64; off <<= 1) {
        int t = __shfl_up(v, off);
        if (lane >= off) v += t;
    }
    __shared__ int ws[4];
    if (lane == 63) ws[wid] = v;
    __syncthreads();
    int add = boff[blockIdx.x];
    for (int w = 0; w < wid; ++w) add += ws[w];
    v += add;
    if (i < NNODES) {
        int ex = v - orig;
        rowptr[i] = ex;
        cursor[i] = ex;
    }
}

__global__ void fill_csr(const int* __restrict__ src, const int* __restrict__ dst,
                         int* __restrict__ cursor, int* __restrict__ srcs) {
    int e = blockIdx.x * blockDim.x + threadIdx.x;
    if (e >= NEDGES) return;
    int p = atomicAdd(&cursor[dst[e]], 1);
    srcs[p] = src[e];
}

// X fp32 [N][523] -> XB bf16 [NPAD][576] (layer 0 only).
// 8 outputs/thread: 32B coalesced read, one 16B vector store.
__global__ __launch_bounds__(256)
void conv_x_v2(const float* __restrict__ X, unsigned short* __restrict__ XB) {
    unsigned t = blockIdx.x * 256 + threadIdx.x;
    unsigned r = t / TPR;
    unsigned c0 = (t % TPR) * 8;
    if (r >= NPAD) return;
    u16x8 o;
    if (r < NNODES) {
        const float* xp = X + (size_t)r * XROW + c0;
        if (c0 + 8 <= XROW) {
#pragma unroll
            for (int q = 0; q < 8; ++q) o[q] = f2bf(xp[q]);
        } else {
#pragma unroll
            for (int q = 0; q < 8; ++q)
                o[q] = (c0 + q < XROW) ? f2bf(xp[q]) : (unsigned short)0;
        }
    } else {
#pragma unroll
        for (int q = 0; q < 8; ++q) o[q] = 0;
    }
    *(u16x8*)(XB + (size_t)r * KP0 + c0) = o;
}

// W fp32 [din][dout] -> Wt bf16 [dout][Kp]
__global__ void conv_wt(const float* __restrict__ W, unsigned short* __restrict__ Wt,
                        int din, int dout, int Kp) {
    int k = blockIdx.x * blockDim.x + threadIdx.x;
    int mcol = blockIdx.y;
    if (k >= Kp) return;
    unsigned short v = 0;
    if (k < din) v = f2bf(W[(size_t)k * dout + mcol]);
    Wt[(size_t)mcol * Kp + k] = v;
}

// ---- MFMA GEMM: C[n][m] = A[n][k] * Bt[m][k]^T, bf16 in / bf16 out ----
// BK=64 (halves barrier drains vs BK=32); LDS tiles XOR-swizzled:
// phys (row, o) holds global col (o ^ ((row&7)*8)) -- applied on the
// global SOURCE addr (global_load_lds dest must stay linear, rule 21)
// and on the ds_read addr. Breaks the 8/16-way bank conflict of the
// row-major 128B-stride tile (lanes 0-15 now hit 8 distinct bank sets).
__global__ __launch_bounds__(256)
void gemm_mfma(const unsigned short* __restrict__ A, const unsigned short* __restrict__ Bt,
               unsigned short* __restrict__ C, int Kp, int m) {
    __shared__ unsigned short sA[128 * 64];
    __shared__ unsigned short sB[128 * 64];
    int tid = threadIdx.x;
    int lane = tid & 63, wave = tid >> 6;
    int wm = (wave & 1) * 64, wn = (wave >> 1) * 64;
    int rowbase = blockIdx.y * 128;
    int colbase = blockIdx.x * 128;

    f32x4 acc[4][4] = {};

    const unsigned short* Ab = A + (size_t)rowbase * Kp;
    const unsigned short* Bb = Bt + (size_t)colbase * Kp;

    // 1024 16B-chunks per matrix: chunk c -> row c>>3, col-off (c&7)*8
    int rr[4], oo[4], osw[4];
#pragma unroll
    for (int j = 0; j < 4; ++j) {
        int c = tid + j * 256;
        rr[j] = c >> 3;
        oo[j] = (c & 7) << 3;
        osw[j] = oo[j] ^ ((rr[j] & 7) << 3);   // pre-swizzled global col
    }

    int arow = wm + (lane & 15);
    int brow = wn + (lane & 15);
    int koff = (lane >> 4) * 8;
    int aswz = (arow & 7) << 3;   // same for all i (i*16 preserves &7)
    int bswz = (brow & 7) << 3;

    for (int k0 = 0; k0 < Kp; k0 += 64) {
#pragma unroll
        for (int j = 0; j < 4; ++j)
            __builtin_amdgcn_global_load_lds(
                (const __attribute__((address_space(1))) void*)(Ab + (size_t)rr[j] * Kp + k0 + osw[j]),
                (__attribute__((address_space(3))) void*)(sA + rr[j] * 64 + oo[j]), 16, 0, 0);
#pragma unroll
        for (int j = 0; j < 4; ++j)
            __builtin_amdgcn_global_load_lds(
                (const __attribute__((address_space(1))) void*)(Bb + (size_t)rr[j] * Kp + k0 + osw[j]),
                (__attribute__((address_space(3))) void*)(sB + rr[j] * 64 + oo[j]), 16, 0, 0);
        __syncthreads();

#pragma unroll
        for (int ks = 0; ks < 64; ks += 32) {
            bf16x8 af[4], bfr[4];
#pragma unroll
            for (int i = 0; i < 4; ++i)
                af[i] = *(const bf16x8*)(sA + (arow + i * 16) * 64 + ((ks + koff) ^ aswz));
#pragma unroll
            for (int i = 0; i < 4; ++i)
                bfr[i] = *(const bf16x8*)(sB + (brow + i * 16) * 64 + ((ks + koff) ^ bswz));
#pragma unroll
            for (int mi = 0; mi < 4; ++mi)
#pragma unroll
                for (int ni = 0; ni < 4; ++ni)
                    acc[mi][ni] = __builtin_amdgcn_mfma_f32_16x16x32_bf16(
                        af[mi], bfr[ni], acc[mi][ni], 0, 0, 0);
        }
        __syncthreads();
    }

    int crow0 = rowbase + wm + (lane >> 4) * 4;
    int ccol0 = colbase + wn + (lane & 15);
#pragma unroll
    for (int mi = 0; mi < 4; ++mi) {
#pragma unroll
        for (int r = 0; r < 4; ++r) {
            int row = crow0 + mi * 16 + r;
            if (row < NNODES) {
#pragma unroll
                for (int ni = 0; ni < 4; ++ni)
                    C[(size_t)row * m + ccol0 + ni * 16] = f2bf(acc[mi][ni][r]);
            }
        }
    }
}

// -------------- attention scalars: one wave per node, coalesced --------------
template <int DOUT>
__global__ __launch_bounds__(256)
void att_scalar_v2(const unsigned short* __restrict__ Wx, const float* __restrict__ a,
                   float* __restrict__ asrc, float* __restrict__ adst) {
    constexpr int HD = DOUT / HEADS;   // 64 or 128
    constexpr int PER = DOUT / 64;     // 4 or 8
    __shared__ float sa[2 * HD];
    int tid = threadIdx.x;
    if (tid < 2 * HD) sa[tid] = a[tid];
    __syncthreads();

    int wave = tid >> 6, lane = tid & 63;
    int node = blockIdx.x * 4 + wave;
    if (node >= NNODES) return;

    int j = lane * PER;
    int h = lane >> 4;                 // head (both DOUT cases)
    int dl = (lane & 15) * PER;        // local d within head
    const unsigned short* base = Wx + (size_t)node * DOUT + j;

    float s1 = 0.f, s2 = 0.f;
#pragma unroll
    for (int t = 0; t < PER; t += 4) {
        u16x4 v4 = *(const u16x4*)(base + t);
#pragma unroll
        for (int q = 0; q < 4; ++q) {
            float v = bf2f(v4[q]);
            s1 = fmaf(v, sa[dl + t + q], s1);
            s2 = fmaf(v, sa[HD + dl + t + q], s2);
        }
    }
    // reduce within 16-lane head groups
#pragma unroll
    for (int off = 1; off < 16; off <<= 1) {
        s1 += __shfl_xor(s1, off);
        s2 += __shfl_xor(s2, off);
    }
    if ((lane & 15) == 0) {
        asrc[node * HEADS + h] = s1;
        adst[node * HEADS + h] = s2;
    }
}

// -------------- fused gather-aggregate + softmax + ELU + LayerNorm -----------
// One wave per node. Lane owns PER contiguous outputs; head h = lane>>4.
// Denominator folded: out = (sum_e exp_e * Wx_src) / (sum_e exp_e + 1e-8).
// nlimit > NNODES (bf16-out case): pad rows [NNODES, nlimit) write zeros
// (replaces the XB-pad memset dispatch).
template <int DOUT, bool OUT_BF>
__global__ __launch_bounds__(256)
void aggregate_wave(const int* __restrict__ rowptr, const int* __restrict__ srcs,
                    const float* __restrict__ asrc, const float* __restrict__ adst,
                    const unsigned short* __restrict__ WxB,
                    const float* __restrict__ g, const float* __restrict__ b,
                    void* __restrict__ outp, int nlimit) {
    constexpr int PER = DOUT / 64;     // 4 (DOUT=256) or 8 (DOUT=512)
    int wid = threadIdx.x >> 6, lane = threadIdx.x & 63;
    int node = blockIdx.x * 4 + wid;
    if (node >= nlimit) return;
    if (node >= NNODES) {              // zero-pad rows (OUT_BF path only)
        if constexpr (OUT_BF) {
            unsigned short* o = (unsigned short*)outp + (size_t)node * DOUT + lane * PER;
            u16x4 z = {0, 0, 0, 0};
            *(u16x4*)o = z;
            if constexpr (PER == 8) *(u16x4*)(o + 4) = z;
        }
        return;
    }

    int h = lane >> 4;                 // head for this lane's output slice
    int li = lane & 15;
    int hb = lane & 48;                // shfl base for this head group
    int beg = rowptr[node], end = rowptr[node + 1];
    float adh = adst[node * HEADS + h];

    const unsigned short* wb = WxB + lane * PER;

    float acc[PER];
#pragma unroll
    for (int q = 0; q < PER; ++q) acc[q] = 0.f;
    float dloc = 0.f;

    typedef __attribute__((ext_vector_type(PER))) unsigned short uvec;

    for (int cb = beg; cb < end; cb += 16) {
        int cnt = min(16, end - cb);
        int s = 0;
        float ex = 0.f;
        if (li < cnt) {
            s = srcs[cb + li];
            float e = asrc[s * HEADS + h] + adh;
            e = e > 0.f ? e : 0.2f * e;
            ex = __expf(e);
        }
        dloc += ex;
        int i = 0;
        for (; i + 4 <= cnt; i += 4) {
            int s0 = __builtin_amdgcn_readlane(s, i);
            int s1 = __builtin_amdgcn_readlane(s, i + 1);
            int s2 = __builtin_amdgcn_readlane(s, i + 2);
            int s3 = __builtin_amdgcn_readlane(s, i + 3);
            uvec v0 = *(const uvec*)(wb + (size_t)s0 * DOUT);
            uvec v1 = *(const uvec*)(wb + (size_t)s1 * DOUT);
            uvec v2 = *(const uvec*)(wb + (size_t)s2 * DOUT);
            uvec v3 = *(const uvec*)(wb + (size_t)s3 * DOUT);
            float w0 = __shfl(ex, hb | i);
            float w1 = __shfl(ex, hb | (i + 1));
            float w2 = __shfl(ex, hb | (i + 2));
            float w3 = __shfl(ex, hb | (i + 3));
#pragma unroll
            for (int q = 0; q < PER; ++q) {
                float t0 = fmaf(w0, bf2f(v0[q]), acc[q]);
                float t1 = fmaf(w1, bf2f(v1[q]), t0);
                float t2 = fmaf(w2, bf2f(v2[q]), t1);
                acc[q] = fmaf(w3, bf2f(v3[q]), t2);
            }
        }
        for (; i < cnt; ++i) {
            int si = __builtin_amdgcn_readlane(s, i);
            uvec v = *(const uvec*)(wb + (size_t)si * DOUT);
            float w = __shfl(ex, hb | i);
#pragma unroll
            for (int q = 0; q < PER; ++q)
                acc[q] = fmaf(w, bf2f(v[q]), acc[q]);
        }
    }

    // reduce per-head denominator across the 16-lane group
    float dsum = dloc;
#pragma unroll
    for (int off = 1; off < 16; off <<= 1) dsum += __shfl_xor(dsum, off);

    float rd = 1.f / (dsum + 1e-8f);
    float vals[PER];
    float lsum = 0.f, lsq = 0.f;
#pragma unroll
    for (int q = 0; q < PER; ++q) {
        float v = acc[q] * rd;
        v = v > 0.f ? v : __expf(v) - 1.f;   // ELU
        vals[q] = v;
        lsum += v;
        lsq = fmaf(v, v, lsq);
    }
#pragma unroll
    for (int off = 1; off < 64; off <<= 1) {
        lsum += __shfl_xor(lsum, off);
        lsq += __shfl_xor(lsq, off);
    }
    float mean = lsum * (1.0f / DOUT);
    float var = lsq * (1.0f / DOUT) - mean * mean;
    float rstd = rsqrtf(var + 1e-5f);

    int j = lane * PER;
    f32x4 g0 = *(const f32x4*)(g + j);
    f32x4 b0 = *(const f32x4*)(b + j);
    float r[PER];
#pragma unroll
    for (int q = 0; q < 4; ++q) r[q] = (vals[q] - mean) * rstd * g0[q] + b0[q];
    if constexpr (PER == 8) {
        f32x4 g1 = *(const f32x4*)(g + j + 4);
        f32x4 b1 = *(const f32x4*)(b + j + 4);
#pragma unroll
        for (int q = 0; q < 4; ++q)
            r[q + 4] = (vals[q + 4] - mean) * rstd * g1[q] + b1[q];
    }

    if constexpr (OUT_BF) {
        unsigned short* o = (unsigned short*)outp + (size_t)node * DOUT + j;
        u16x4 o0;
#pragma unroll
        for (int q = 0; q < 4; ++q) o0[q] = f2bf(r[q]);
        *(u16x4*)o = o0;
        if constexpr (PER == 8) {
            u16x4 o1;
#pragma unroll
            for (int q = 0; q < 4; ++q) o1[q] = f2bf(r[q + 4]);
            *(u16x4*)(o + 4) = o1;
        }
    } else {
        float* o = (float*)outp + (size_t)node * DOUT + j;
        f32x4 v0 = {r[0], r[1], r[2], r[3]};
        *(f32x4*)o = v0;
        if constexpr (PER == 8) {
            f32x4 v1 = {r[4], r[5], r[6], r[7]};
            *(f32x4*)(o + 4) = v1;
        }
    }
}

extern "C" void kernel_launch(void* const* d_in, const int* in_sizes, int n_in,
                              void* d_out, int out_size, void* d_ws, size_t ws_size,
                              hipStream_t stream) {
    const float* x0 = (const float*)d_in[0];
    const int* ei = (const int*)d_in[1];
    const int* src = ei;
    const int* dst = ei + NEDGES;
    const float* W[3]  = {(const float*)d_in[2], (const float*)d_in[6],  (const float*)d_in[10]};
    const float* a[3]  = {(const float*)d_in[3], (const float*)d_in[7],  (const float*)d_in[11]};
    const float* g[3]  = {(const float*)d_in[4], (const float*)d_in[8],  (const float*)d_in[12]};
    const float* bb[3] = {(const float*)d_in[5], (const float*)d_in[9],  (const float*)d_in[13]};

    char* p = (char*)d_ws;
    auto carve = [&](size_t bytes) {
        char* r = p;
        p += (bytes + 255) & ~(size_t)255;
        return r;
    };
    unsigned short* XB   = (unsigned short*)carve((size_t)NPAD * KP0 * 2);
    unsigned short* WxB  = (unsigned short*)carve((size_t)NNODES * 512 * 2);
    unsigned short* Wt   = (unsigned short*)carve((size_t)512 * KP0 * 2);
    float* ASRC  = (float*)carve((size_t)NNODES * HEADS * 4);
    float* ADST  = (float*)carve((size_t)NNODES * HEADS * 4);
    int* CNT  = (int*)carve((size_t)NNODES * 4);
    int* ROWP = (int*)carve((size_t)(NNODES + 1) * 4);
    int* CURS = (int*)carve((size_t)NNODES * 4);
    int* SRCS = (int*)carve((size_t)NEDGES * 4);
    int* BSUM = (int*)carve(256 * 4);
    int* BOFF = (int*)carve(256 * 4);

    hipMemsetAsync(CNT, 0, (size_t)NNODES * 4, stream);
    count_deg<<<(NEDGES + 255) / 256, 256, 0, stream>>>(dst, CNT);
    scan_p1<<<NSCAN_BLK, 256, 0, stream>>>(CNT, BSUM);
    scan_p2<<<1, 256, 0, stream>>>(BSUM, BOFF, ROWP);
    scan_p3<<<NSCAN_BLK, 256, 0, stream>>>(CNT, BOFF, ROWP, CURS);
    fill_csr<<<(NEDGES + 255) / 256, 256, 0, stream>>>(src, dst, CURS, SRCS);

    const int dims[4] = {523, 256, 256, 512};
    const int Kps[3] = {KP0, 256, 256};
    for (int li = 0; li < 3; ++li) {
        int din = dims[li], dout = dims[li + 1];
        int Kp = Kps[li];

        if (li == 0) {
            conv_x_v2<<<(NPAD * TPR) / 256, 256, 0, stream>>>(x0, XB);
        }
        conv_wt<<<dim3((Kp + 255) / 256, dout), 256, 0, stream>>>(W[li], Wt, din, dout, Kp);

        gemm_mfma<<<dim3(dout / 128, NPAD / 128), 256, 0, stream>>>(XB, Wt, WxB, Kp, dout);

        if (dout == 256)
            att_scalar_v2<256><<<(NNODES + 3) / 4, 256, 0, stream>>>(WxB, a[li], ASRC, ADST);
        else
            att_scalar_v2<512><<<(NNODES + 3) / 4, 256, 0, stream>>>(WxB, a[li], ASRC, ADST);

        if (li == 2) {
            aggregate_wave<512, false><<<(NNODES + 3) / 4, 256, 0, stream>>>(
                ROWP, SRCS, ASRC, ADST, WxB, g[li], bb[li], d_out, NNODES);
        } else {
            aggregate_wave<256, true><<<(NPAD + 3) / 4, 256, 0, stream>>>(
                ROWP, SRCS, ASRC, ADST, WxB, g[li], bb[li], (void*)XB, NPAD);
        }
    }
}

// Round 6
// 512.443 us; speedup vs baseline: 1.0705x; 1.0035x over previous
//
#include <hip/hip_runtime.h>
#include <math.h>

#define NNODES 50000
#define NEDGES 400000
#define HEADS 4
#define NPAD 50048       // 391 * 128
#define NSCAN_BLK 196    // ceil(NNODES/256)
#define XROW 523
#define KP0 576          // K padded to multiple of 64 for BK=64 GEMM
#define TPR 72           // threads per row in conv_x_v2 (576/8)

typedef __attribute__((ext_vector_type(8))) short bf16x8;
typedef __attribute__((ext_vector_type(4))) float f32x4;
typedef __attribute__((ext_vector_type(4))) unsigned short u16x4;
typedef __attribute__((ext_vector_type(8))) unsigned short u16x8;

__device__ inline unsigned short f2bf(float f) {
    union { float f; unsigned u; } t; t.f = f;
    unsigned u = t.u;
    u += 0x7fffu + ((u >> 16) & 1u);
    return (unsigned short)(u >> 16);
}
__device__ inline float bf2f(unsigned short s) {
    union { unsigned u; float f; } t; t.u = ((unsigned)s) << 16;
    return t.f;
}

// ---------------- CSR build (edge_index is constant across layers) -----------
__global__ void count_deg(const int* __restrict__ dst, int* __restrict__ cnt) {
    int e = blockIdx.x * blockDim.x + threadIdx.x;
    if (e < NEDGES) atomicAdd(&cnt[dst[e]], 1);
}

// ---- parallel exclusive scan over cnt[NNODES]: 3 tiny kernels ----
__global__ __launch_bounds__(256)
void scan_p1(const int* __restrict__ cnt, int* __restrict__ bsum) {
    int i = blockIdx.x * 256 + threadIdx.x;
    int v = (i < NNODES) ? cnt[i] : 0;
#pragma unroll
    for (int off = 1; off < 64; off <<= 1) v += __shfl_xor(v, off);
    __shared__ int ws[4];
    if ((threadIdx.x & 63) == 0) ws[threadIdx.x >> 6] = v;
    __syncthreads();
    if (threadIdx.x == 0) bsum[blockIdx.x] = ws[0] + ws[1] + ws[2] + ws[3];
}

__global__ __launch_bounds__(256)
void scan_p2(const int* __restrict__ bsum, int* __restrict__ boff,
             int* __restrict__ rowptr) {
    int tid = threadIdx.x;
    int v = (tid < NSCAN_BLK) ? bsum[tid] : 0;
    int orig = v;
    int lane = tid & 63, wid = tid >> 6;
#pragma unroll
    for (int off = 1; off < 64; off <<= 1) {
        int t = __shfl_up(v, off);
        if (lane >= off) v += t;
    }
    __shared__ int ws[4];
    if (lane == 63) ws[wid] = v;
    __syncthreads();
    int add = 0;
    for (int w = 0; w < wid; ++w) add += ws[w];
    v += add;
    if (tid < NSCAN_BLK) boff[tid] = v - orig;   // exclusive block offset
    if (tid == 255) rowptr[NNODES] = v;          // grand total
}

__global__ __launch_bounds__(256)
void scan_p3(const int* __restrict__ cnt, const int* __restrict__ boff,
             int* __restrict__ rowptr, int* __restrict__ cursor) {
    int i = blockIdx.x * 256 + threadIdx.x;
    int v = (i < NNODES) ? cnt[i] : 0;
    int orig = v;
    int lane = threadIdx.x & 63, wid = threadIdx.x >> 6;
#pragma unroll
    for (int off = 1; off < 64; off <<= 1) {
        int t = __shfl_up(v, off);
        if (lane >= off) v += t;
    }
    __shared__ int ws[4];
    if (lane == 63) ws[wid] = v;
    __syncthreads();
    int add = boff[blockIdx.x];
    for (int w = 0; w < wid; ++w) add += ws[w];
    v += add;
    if (i < NNODES) {
        int ex = v - orig;
        rowptr[i] = ex;
        cursor[i] = ex;
    }
}

__global__ void fill_csr(const int* __restrict__ src, const int* __restrict__ dst,
                         int* __restrict__ cursor, int* __restrict__ srcs) {
    int e = blockIdx.x * blockDim.x + threadIdx.x;
    if (e >= NEDGES) return;
    int p = atomicAdd(&cursor[dst[e]], 1);
    srcs[p] = src[e];
}

// X fp32 [N][523] -> XB bf16 [NPAD][576] (layer 0 only).
// 8 outputs/thread: 32B coalesced read, one 16B vector store.
__global__ __launch_bounds__(256)
void conv_x_v2(const float* __restrict__ X, unsigned short* __restrict__ XB) {
    unsigned t = blockIdx.x * 256 + threadIdx.x;
    unsigned r = t / TPR;
    unsigned c0 = (t % TPR) * 8;
    if (r >= NPAD) return;
    u16x8 o;
    if (r < NNODES) {
        const float* xp = X + (size_t)r * XROW + c0;
        if (c0 + 8 <= XROW) {
#pragma unroll
            for (int q = 0; q < 8; ++q) o[q] = f2bf(xp[q]);
        } else {
#pragma unroll
            for (int q = 0; q < 8; ++q)
                o[q] = (c0 + q < XROW) ? f2bf(xp[q]) : (unsigned short)0;
        }
    } else {
#pragma unroll
        for (int q = 0; q < 8; ++q) o[q] = 0;
    }
    *(u16x8*)(XB + (size_t)r * KP0 + c0) = o;
}

// W fp32 [din][dout] -> Wt bf16 [dout][Kp]
__global__ void conv_wt(const float* __restrict__ W, unsigned short* __restrict__ Wt,
                        int din, int dout, int Kp) {
    int k = blockIdx.x * blockDim.x + threadIdx.x;
    int mcol = blockIdx.y;
    if (k >= Kp) return;
    unsigned short v = 0;
    if (k < din) v = f2bf(W[(size_t)k * dout + mcol]);
    Wt[(size_t)mcol * Kp + k] = v;
}

// ---- MFMA GEMM: C[n][m] = A[n][k] * Bt[m][k]^T, bf16 in / bf16 out ----
// BK=64; LDS XOR-swizzle both-sides (see round-4 comment).
// Flat 1-D grid with XCD-pinned sibling swizzle: all col-blocks x of a
// node-block y satisfy g%8 == y%8 -> same XCD (bid%8 round-robin, m09),
// a few dispatch slots apart -> the shared 128-row A-panel is L2-hot for
// the siblings instead of re-fetched from HBM per col-block.
__global__ __launch_bounds__(256)
void gemm_mfma(const unsigned short* __restrict__ A, const unsigned short* __restrict__ Bt,
               unsigned short* __restrict__ C, int Kp, int m) {
    __shared__ unsigned short sA[128 * 64];
    __shared__ unsigned short sB[128 * 64];
    int tid = threadIdx.x;
    int lane = tid & 63, wave = tid >> 6;
    int wm = (wave & 1) * 64, wn = (wave >> 1) * 64;

    // decode flat block id -> (x = col-block, y = node-block), XCD-pinned
    int XC = m >> 7;                       // 2 or 4 col-blocks
    int xs = (XC == 4) ? 2 : 1;            // log2(XC)
    int g = blockIdx.x;
    int x, y;
    int mainN = (XC << 3) * 48;            // covers y in [0, 384)
    if (g < mainN) {
        int r = g & 7, q = g >> 3;
        x = q & (XC - 1);
        y = ((q >> xs) << 3) | r;
    } else {                               // tail: y in [384, 391)
        int gp = g - mainN;
        y = 384 + (gp >> xs);
        x = gp & (XC - 1);
    }
    int rowbase = y << 7;
    int colbase = x << 7;

    f32x4 acc[4][4] = {};

    const unsigned short* Ab = A + (size_t)rowbase * Kp;
    const unsigned short* Bb = Bt + (size_t)colbase * Kp;

    // 1024 16B-chunks per matrix: chunk c -> row c>>3, col-off (c&7)*8
    int rr[4], oo[4], osw[4];
#pragma unroll
    for (int j = 0; j < 4; ++j) {
        int c = tid + j * 256;
        rr[j] = c >> 3;
        oo[j] = (c & 7) << 3;
        osw[j] = oo[j] ^ ((rr[j] & 7) << 3);   // pre-swizzled global col
    }

    int arow = wm + (lane & 15);
    int brow = wn + (lane & 15);
    int koff = (lane >> 4) * 8;
    int aswz = (arow & 7) << 3;   // same for all i (i*16 preserves &7)
    int bswz = (brow & 7) << 3;

    for (int k0 = 0; k0 < Kp; k0 += 64) {
#pragma unroll
        for (int j = 0; j < 4; ++j)
            __builtin_amdgcn_global_load_lds(
                (const __attribute__((address_space(1))) void*)(Ab + (size_t)rr[j] * Kp + k0 + osw[j]),
                (__attribute__((address_space(3))) void*)(sA + rr[j] * 64 + oo[j]), 16, 0, 0);
#pragma unroll
        for (int j = 0; j < 4; ++j)
            __builtin_amdgcn_global_load_lds(
                (const __attribute__((address_space(1))) void*)(Bb + (size_t)rr[j] * Kp + k0 + osw[j]),
                (__attribute__((address_space(3))) void*)(sB + rr[j] * 64 + oo[j]), 16, 0, 0);
        __syncthreads();

#pragma unroll
        for (int ks = 0; ks < 64; ks += 32) {
            bf16x8 af[4], bfr[4];
#pragma unroll
            for (int i = 0; i < 4; ++i)
                af[i] = *(const bf16x8*)(sA + (arow + i * 16) * 64 + ((ks + koff) ^ aswz));
#pragma unroll
            for (int i = 0; i < 4; ++i)
                bfr[i] = *(const bf16x8*)(sB + (brow + i * 16) * 64 + ((ks + koff) ^ bswz));
#pragma unroll
            for (int mi = 0; mi < 4; ++mi)
#pragma unroll
                for (int ni = 0; ni < 4; ++ni)
                    acc[mi][ni] = __builtin_amdgcn_mfma_f32_16x16x32_bf16(
                        af[mi], bfr[ni], acc[mi][ni], 0, 0, 0);
        }
        __syncthreads();
    }

    int crow0 = rowbase + wm + (lane >> 4) * 4;
    int ccol0 = colbase + wn + (lane & 15);
#pragma unroll
    for (int mi = 0; mi < 4; ++mi) {
#pragma unroll
        for (int r = 0; r < 4; ++r) {
            int row = crow0 + mi * 16 + r;
            if (row < NNODES) {
#pragma unroll
                for (int ni = 0; ni < 4; ++ni)
                    C[(size_t)row * m + ccol0 + ni * 16] = f2bf(acc[mi][ni][r]);
            }
        }
    }
}

// -------------- attention scalars: one wave per node, coalesced --------------
template <int DOUT>
__global__ __launch_bounds__(256)
void att_scalar_v2(const unsigned short* __restrict__ Wx, const float* __restrict__ a,
                   float* __restrict__ asrc, float* __restrict__ adst) {
    constexpr int HD = DOUT / HEADS;   // 64 or 128
    constexpr int PER = DOUT / 64;     // 4 or 8
    __shared__ float sa[2 * HD];
    int tid = threadIdx.x;
    if (tid < 2 * HD) sa[tid] = a[tid];
    __syncthreads();

    int wave = tid >> 6, lane = tid & 63;
    int node = blockIdx.x * 4 + wave;
    if (node >= NNODES) return;

    int j = lane * PER;
    int h = lane >> 4;                 // head (both DOUT cases)
    int dl = (lane & 15) * PER;        // local d within head
    const unsigned short* base = Wx + (size_t)node * DOUT + j;

    float s1 = 0.f, s2 = 0.f;
#pragma unroll
    for (int t = 0; t < PER; t += 4) {
        u16x4 v4 = *(const u16x4*)(base + t);
#pragma unroll
        for (int q = 0; q < 4; ++q) {
            float v = bf2f(v4[q]);
            s1 = fmaf(v, sa[dl + t + q], s1);
            s2 = fmaf(v, sa[HD + dl + t + q], s2);
        }
    }
    // reduce within 16-lane head groups
#pragma unroll
    for (int off = 1; off < 16; off <<= 1) {
        s1 += __shfl_xor(s1, off);
        s2 += __shfl_xor(s2, off);
    }
    if ((lane & 15) == 0) {
        asrc[node * HEADS + h] = s1;
        adst[node * HEADS + h] = s2;
    }
}

// -------------- fused gather-aggregate + softmax + ELU + LayerNorm -----------
// One wave per node. Lane owns PER contiguous outputs; head h = lane>>4.
// Denominator folded: out = (sum_e exp_e * Wx_src) / (sum_e exp_e + 1e-8).
// nlimit > NNODES (bf16-out case): pad rows [NNODES, nlimit) write zeros.
// fp32-out (final layer): nontemporal stores -- d_out is 100MB never re-read;
// keeping it out of L2 preserves capacity for the random WxB gather.
template <int DOUT, bool OUT_BF>
__global__ __launch_bounds__(256)
void aggregate_wave(const int* __restrict__ rowptr, const int* __restrict__ srcs,
                    const float* __restrict__ asrc, const float* __restrict__ adst,
                    const unsigned short* __restrict__ WxB,
                    const float* __restrict__ g, const float* __restrict__ b,
                    void* __restrict__ outp, int nlimit) {
    constexpr int PER = DOUT / 64;     // 4 (DOUT=256) or 8 (DOUT=512)
    int wid = threadIdx.x >> 6, lane = threadIdx.x & 63;
    int node = blockIdx.x * 4 + wid;
    if (node >= nlimit) return;
    if (node >= NNODES) {              // zero-pad rows (OUT_BF path only)
        if constexpr (OUT_BF) {
            unsigned short* o = (unsigned short*)outp + (size_t)node * DOUT + lane * PER;
            u16x4 z = {0, 0, 0, 0};
            *(u16x4*)o = z;
            if constexpr (PER == 8) *(u16x4*)(o + 4) = z;
        }
        return;
    }

    int h = lane >> 4;                 // head for this lane's output slice
    int li = lane & 15;
    int hb = lane & 48;                // shfl base for this head group
    int beg = rowptr[node], end = rowptr[node + 1];
    float adh = adst[node * HEADS + h];

    const unsigned short* wb = WxB + lane * PER;

    float acc[PER];
#pragma unroll
    for (int q = 0; q < PER; ++q) acc[q] = 0.f;
    float dloc = 0.f;

    typedef __attribute__((ext_vector_type(PER))) unsigned short uvec;

    for (int cb = beg; cb < end; cb += 16) {
        int cnt = min(16, end - cb);
        int s = 0;
        float ex = 0.f;
        if (li < cnt) {
            s = srcs[cb + li];
            float e = asrc[s * HEADS + h] + adh;
            e = e > 0.f ? e : 0.2f * e;
            ex = __expf(e);
        }
        dloc += ex;
        int i = 0;
        for (; i + 4 <= cnt; i += 4) {
            int s0 = __builtin_amdgcn_readlane(s, i);
            int s1 = __builtin_amdgcn_readlane(s, i + 1);
            int s2 = __builtin_amdgcn_readlane(s, i + 2);
            int s3 = __builtin_amdgcn_readlane(s, i + 3);
            uvec v0 = *(const uvec*)(wb + (size_t)s0 * DOUT);
            uvec v1 = *(const uvec*)(wb + (size_t)s1 * DOUT);
            uvec v2 = *(const uvec*)(wb + (size_t)s2 * DOUT);
            uvec v3 = *(const uvec*)(wb + (size_t)s3 * DOUT);
            float w0 = __shfl(ex, hb | i);
            float w1 = __shfl(ex, hb | (i + 1));
            float w2 = __shfl(ex, hb | (i + 2));
            float w3 = __shfl(ex, hb | (i + 3));
#pragma unroll
            for (int q = 0; q < PER; ++q) {
                float t0 = fmaf(w0, bf2f(v0[q]), acc[q]);
                float t1 = fmaf(w1, bf2f(v1[q]), t0);
                float t2 = fmaf(w2, bf2f(v2[q]), t1);
                acc[q] = fmaf(w3, bf2f(v3[q]), t2);
            }
        }
        for (; i < cnt; ++i) {
            int si = __builtin_amdgcn_readlane(s, i);
            uvec v = *(const uvec*)(wb + (size_t)si * DOUT);
            float w = __shfl(ex, hb | i);
#pragma unroll
            for (int q = 0; q < PER; ++q)
                acc[q] = fmaf(w, bf2f(v[q]), acc[q]);
        }
    }

    // reduce per-head denominator across the 16-lane group
    float dsum = dloc;
#pragma unroll
    for (int off = 1; off < 16; off <<= 1) dsum += __shfl_xor(dsum, off);

    float rd = 1.f / (dsum + 1e-8f);
    float vals[PER];
    float lsum = 0.f, lsq = 0.f;
#pragma unroll
    for (int q = 0; q < PER; ++q) {
        float v = acc[q] * rd;
        v = v > 0.f ? v : __expf(v) - 1.f;   // ELU
        vals[q] = v;
        lsum += v;
        lsq = fmaf(v, v, lsq);
    }
#pragma unroll
    for (int off = 1; off < 64; off <<= 1) {
        lsum += __shfl_xor(lsum, off);
        lsq += __shfl_xor(lsq, off);
    }
    float mean = lsum * (1.0f / DOUT);
    float var = lsq * (1.0f / DOUT) - mean * mean;
    float rstd = rsqrtf(var + 1e-5f);

    int j = lane * PER;
    f32x4 g0 = *(const f32x4*)(g + j);
    f32x4 b0 = *(const f32x4*)(b + j);
    float r[PER];
#pragma unroll
    for (int q = 0; q < 4; ++q) r[q] = (vals[q] - mean) * rstd * g0[q] + b0[q];
    if constexpr (PER == 8) {
        f32x4 g1 = *(const f32x4*)(g + j + 4);
        f32x4 b1 = *(const f32x4*)(b + j + 4);
#pragma unroll
        for (int q = 0; q < 4; ++q)
            r[q + 4] = (vals[q + 4] - mean) * rstd * g1[q] + b1[q];
    }

    if constexpr (OUT_BF) {
        unsigned short* o = (unsigned short*)outp + (size_t)node * DOUT + j;
        u16x4 o0;
#pragma unroll
        for (int q = 0; q < 4; ++q) o0[q] = f2bf(r[q]);
        *(u16x4*)o = o0;
        if constexpr (PER == 8) {
            u16x4 o1;
#pragma unroll
            for (int q = 0; q < 4; ++q) o1[q] = f2bf(r[q + 4]);
            *(u16x4*)(o + 4) = o1;
        }
    } else {
        float* o = (float*)outp + (size_t)node * DOUT + j;
        f32x4 v0 = {r[0], r[1], r[2], r[3]};
        __builtin_nontemporal_store(v0, (f32x4*)o);
        if constexpr (PER == 8) {
            f32x4 v1 = {r[4], r[5], r[6], r[7]};
            __builtin_nontemporal_store(v1, (f32x4*)(o + 4));
        }
    }
}

extern "C" void kernel_launch(void* const* d_in, const int* in_sizes, int n_in,
                              void* d_out, int out_size, void* d_ws, size_t ws_size,
                              hipStream_t stream) {
    const float* x0 = (const float*)d_in[0];
    const int* ei = (const int*)d_in[1];
    const int* src = ei;
    const int* dst = ei + NEDGES;
    const float* W[3]  = {(const float*)d_in[2], (const float*)d_in[6],  (const float*)d_in[10]};
    const float* a[3]  = {(const float*)d_in[3], (const float*)d_in[7],  (const float*)d_in[11]};
    const float* g[3]  = {(const float*)d_in[4], (const float*)d_in[8],  (const float*)d_in[12]};
    const float* bb[3] = {(const float*)d_in[5], (const float*)d_in[9],  (const float*)d_in[13]};

    char* p = (char*)d_ws;
    auto carve = [&](size_t bytes) {
        char* r = p;
        p += (bytes + 255) & ~(size_t)255;
        return r;
    };
    unsigned short* XB   = (unsigned short*)carve((size_t)NPAD * KP0 * 2);
    unsigned short* WxB  = (unsigned short*)carve((size_t)NNODES * 512 * 2);
    unsigned short* Wt   = (unsigned short*)carve((size_t)512 * KP0 * 2);
    float* ASRC  = (float*)carve((size_t)NNODES * HEADS * 4);
    float* ADST  = (float*)carve((size_t)NNODES * HEADS * 4);
    int* CNT  = (int*)carve((size_t)NNODES * 4);
    int* ROWP = (int*)carve((size_t)(NNODES + 1) * 4);
    int* CURS = (int*)carve((size_t)NNODES * 4);
    int* SRCS = (int*)carve((size_t)NEDGES * 4);
    int* BSUM = (int*)carve(256 * 4);
    int* BOFF = (int*)carve(256 * 4);

    hipMemsetAsync(CNT, 0, (size_t)NNODES * 4, stream);
    count_deg<<<(NEDGES + 255) / 256, 256, 0, stream>>>(dst, CNT);
    scan_p1<<<NSCAN_BLK, 256, 0, stream>>>(CNT, BSUM);
    scan_p2<<<1, 256, 0, stream>>>(BSUM, BOFF, ROWP);
    scan_p3<<<NSCAN_BLK, 256, 0, stream>>>(CNT, BOFF, ROWP, CURS);
    fill_csr<<<(NEDGES + 255) / 256, 256, 0, stream>>>(src, dst, CURS, SRCS);

    const int dims[4] = {523, 256, 256, 512};
    const int Kps[3] = {KP0, 256, 256};
    for (int li = 0; li < 3; ++li) {
        int din = dims[li], dout = dims[li + 1];
        int Kp = Kps[li];

        if (li == 0) {
            conv_x_v2<<<(NPAD * TPR) / 256, 256, 0, stream>>>(x0, XB);
        }
        conv_wt<<<dim3((Kp + 255) / 256, dout), 256, 0, stream>>>(W[li], Wt, din, dout, Kp);

        gemm_mfma<<<dim3((dout / 128) * (NPAD / 128)), 256, 0, stream>>>(XB, Wt, WxB, Kp, dout);

        if (dout == 256)
            att_scalar_v2<256><<<(NNODES + 3) / 4, 256, 0, stream>>>(WxB, a[li], ASRC, ADST);
        else
            att_scalar_v2<512><<<(NNODES + 3) / 4, 256, 0, stream>>>(WxB, a[li], ASRC, ADST);

        if (li == 2) {
            aggregate_wave<512, false><<<(NNODES + 3) / 4, 256, 0, stream>>>(
                ROWP, SRCS, ASRC, ADST, WxB, g[li], bb[li], d_out, NNODES);
        } else {
            aggregate_wave<256, true><<<(NPAD + 3) / 4, 256, 0, stream>>>(
                ROWP, SRCS, ASRC, ADST, WxB, g[li], bb[li], (void*)XB, NPAD);
        }
    }
}

// Round 8
// 496.084 us; speedup vs baseline: 1.1058x; 1.0330x over previous
//
#include <hip/hip_runtime.h>
#include <math.h>

#define NNODES 50000
#define NEDGES 400000
#define HEADS 4
#define NPAD 50048       // 391 * 128
#define NSCAN_BLK 196    // ceil(NNODES/256)
#define XROW 523
#define KP0 576          // K padded to multiple of 64 for BK=64 GEMM
#define TPR 72           // threads per row in conv_x_v2 (576/8)

typedef __attribute__((ext_vector_type(8))) short bf16x8;
typedef __attribute__((ext_vector_type(4))) float f32x4;
typedef __attribute__((ext_vector_type(4))) unsigned short u16x4;
typedef __attribute__((ext_vector_type(8))) unsigned short u16x8;

__device__ inline unsigned short f2bf(float f) {
    union { float f; unsigned u; } t; t.f = f;
    unsigned u = t.u;
    u += 0x7fffu + ((u >> 16) & 1u);
    return (unsigned short)(u >> 16);
}
__device__ inline float bf2f(unsigned short s) {
    union { unsigned u; float f; } t; t.u = ((unsigned)s) << 16;
    return t.f;
}

// ---------------- CSR build (edge_index is constant across layers) -----------
__global__ void count_deg(const int* __restrict__ dst, int* __restrict__ cnt) {
    int e = blockIdx.x * blockDim.x + threadIdx.x;
    if (e < NEDGES) atomicAdd(&cnt[dst[e]], 1);
}

// ---- parallel exclusive scan over cnt[NNODES]: 3 tiny kernels ----
__global__ __launch_bounds__(256)
void scan_p1(const int* __restrict__ cnt, int* __restrict__ bsum) {
    int i = blockIdx.x * 256 + threadIdx.x;
    int v = (i < NNODES) ? cnt[i] : 0;
#pragma unroll
    for (int off = 1; off < 64; off <<= 1) v += __shfl_xor(v, off);
    __shared__ int ws[4];
    if ((threadIdx.x & 63) == 0) ws[threadIdx.x >> 6] = v;
    __syncthreads();
    if (threadIdx.x == 0) bsum[blockIdx.x] = ws[0] + ws[1] + ws[2] + ws[3];
}

__global__ __launch_bounds__(256)
void scan_p2(const int* __restrict__ bsum, int* __restrict__ boff,
             int* __restrict__ rowptr) {
    int tid = threadIdx.x;
    int v = (tid < NSCAN_BLK) ? bsum[tid] : 0;
    int orig = v;
    int lane = tid & 63, wid = tid >> 6;
#pragma unroll
    for (int off = 1; off < 64; off <<= 1) {
        int t = __shfl_up(v, off);
        if (lane >= off) v += t;
    }
    __shared__ int ws[4];
    if (lane == 63) ws[wid] = v;
    __syncthreads();
    int add = 0;
    for (int w = 0; w < wid; ++w) add += ws[w];
    v += add;
    if (tid < NSCAN_BLK) boff[tid] = v - orig;   // exclusive block offset
    if (tid == 255) rowptr[NNODES] = v;          // grand total
}

__global__ __launch_bounds__(256)
void scan_p3(const int* __restrict__ cnt, const int* __restrict__ boff,
             int* __restrict__ rowptr, int* __restrict__ cursor) {
    int i = blockIdx.x * 256 + threadIdx.x;
    int v = (i < NNODES) ? cnt[i] : 0;
    int orig = v;
    int lane = threadIdx.x & 63, wid = threadIdx.x >> 6;
#pragma unroll
    for (int off = 1; off < 64; off <<= 1) {
        int t = __shfl_up(v, off);
        if (lane >= off) v += t;
    }
    __shared__ int ws[4];
    if (lane == 63) ws[wid] = v;
    __syncthreads();
    int add = boff[blockIdx.x];
    for (int w = 0; w < wid; ++w) add += ws[w];
    v += add;
    if (i < NNODES) {
        int ex = v - orig;
        rowptr[i] = ex;
        cursor[i] = ex;
    }
}

__global__ void fill_csr(const int* __restrict__ src, const int* __restrict__ dst,
                         int* __restrict__ cursor, int* __restrict__ srcs) {
    int e = blockIdx.x * blockDim.x + threadIdx.x;
    if (e >= NEDGES) return;
    int p = atomicAdd(&cursor[dst[e]], 1);
    srcs[p] = src[e];
}

// X fp32 [N][523] -> XB bf16 [NNODES][576] (layer 0 only).
// Pad rows [NNODES, NPAD) stay garbage: GEMM drops their outputs (row guard).
__global__ __launch_bounds__(256)
void conv_x_v2(const float* __restrict__ X, unsigned short* __restrict__ XB) {
    unsigned t = blockIdx.x * 256 + threadIdx.x;
    unsigned r = t / TPR;
    unsigned c0 = (t % TPR) * 8;
    if (r >= NNODES) return;
    u16x8 o;
    const float* xp = X + (size_t)r * XROW + c0;
    if (c0 + 8 <= XROW) {
#pragma unroll
        for (int q = 0; q < 8; ++q) o[q] = f2bf(xp[q]);
    } else {
#pragma unroll
        for (int q = 0; q < 8; ++q)
            o[q] = (c0 + q < XROW) ? f2bf(xp[q]) : (unsigned short)0;
    }
    *(u16x8*)(XB + (size_t)r * KP0 + c0) = o;
}

// All three W fp32 [din][dout] -> Wt bf16 [dout][Kp], one launch.
#define SEG0 (256 * 576)
#define SEG1 (256 * 256)
#define SEG2 (512 * 256)
__global__ __launch_bounds__(256)
void conv_wt_all(const float* __restrict__ W0, const float* __restrict__ W1,
                 const float* __restrict__ W2, unsigned short* __restrict__ T0,
                 unsigned short* __restrict__ T1, unsigned short* __restrict__ T2) {
    int gid = blockIdx.x * 256 + threadIdx.x;
    const float* W; unsigned short* T; int din, dout, Kp, idx;
    if (gid < SEG0)               { W = W0; T = T0; din = 523; dout = 256; Kp = 576; idx = gid; }
    else if (gid < SEG0 + SEG1)   { W = W1; T = T1; din = 256; dout = 256; Kp = 256; idx = gid - SEG0; }
    else if (gid < SEG0 + SEG1 + SEG2) { W = W2; T = T2; din = 256; dout = 512; Kp = 256; idx = gid - SEG0 - SEG1; }
    else return;
    int mcol = idx / Kp, k = idx - mcol * Kp;
    unsigned short v = 0;
    if (k < din) v = f2bf(W[(size_t)k * dout + mcol]);
    T[(size_t)mcol * Kp + k] = v;
}

// ---- MFMA GEMM: C[n][m] = A[n][k] * Bt[m][k]^T, bf16 in / bf16 out ----
// BM=128, BN=256, BK=64, 512 threads (8 waves, 2m x 4n).
// Staging chunk budget (16B = 8 bf16): sA 128x64 = 1024 chunks -> 2/thread;
// sB 256x64 = 2048 chunks -> 4/thread.  (Round-7 bug: half-staged tiles.)
// dout=256: whole B per block -> A read exactly once. dout=512: 2 col-blocks,
// XCD-pinned siblings (g%8 == y%8) for A-panel L2 reuse.
// LDS XOR-swizzled both-sides: phys (row,o) holds global col o^((row&7)*8).
__global__ __launch_bounds__(512)
void gemm_mfma(const unsigned short* __restrict__ A, const unsigned short* __restrict__ Bt,
               unsigned short* __restrict__ C, int Kp, int m) {
    __shared__ unsigned short sA[128 * 64];   // 16 KB
    __shared__ unsigned short sB[256 * 64];   // 32 KB
    int tid = threadIdx.x;
    int lane = tid & 63, wave = tid >> 6;
    int wm = (wave & 1) * 64, wn = (wave >> 1) * 64;   // wn in {0,64,128,192}

    // decode flat block id -> (x = col-block, y = node-block)
    int XC = m >> 8;                       // 1 (dout=256) or 2 (dout=512)
    int g = blockIdx.x;
    int x, y;
    if (XC == 1) {
        x = 0; y = g;
    } else {
        int mainN = 768;                   // covers y in [0,384)
        if (g < mainN) {
            int r = g & 7, q = g >> 3;
            x = q & 1;
            y = ((q >> 1) << 3) | r;
        } else {
            int gp = g - mainN;
            y = 384 + (gp >> 1);
            x = gp & 1;
        }
    }
    int rowbase = y << 7;
    int colbase = x << 8;

    f32x4 acc[4][4] = {};

    const unsigned short* Ab = A + (size_t)rowbase * Kp;
    const unsigned short* Bb = Bt + (size_t)colbase * Kp;

    // chunk c -> row c>>3, col-off (c&7)*8, source col pre-swizzled
    int raj[2], oaj[2], oswaj[2];
#pragma unroll
    for (int j = 0; j < 2; ++j) {
        int c = tid + j * 512;             // 0..1023 -> rows 0..127
        raj[j] = c >> 3;
        oaj[j] = (c & 7) << 3;
        oswaj[j] = oaj[j] ^ ((raj[j] & 7) << 3);
    }
    int rbj[4], obj[4], oswbj[4];
#pragma unroll
    for (int j = 0; j < 4; ++j) {
        int c = tid + j * 512;             // 0..2047 -> rows 0..255
        rbj[j] = c >> 3;
        obj[j] = (c & 7) << 3;
        oswbj[j] = obj[j] ^ ((rbj[j] & 7) << 3);
    }

    int arow = wm + (lane & 15);
    int brow = wn + (lane & 15);
    int koff = (lane >> 4) * 8;
    int aswz = (arow & 7) << 3;   // i*16 preserves &7
    int bswz = (brow & 7) << 3;

    for (int k0 = 0; k0 < Kp; k0 += 64) {
#pragma unroll
        for (int j = 0; j < 2; ++j)
            __builtin_amdgcn_global_load_lds(
                (const __attribute__((address_space(1))) void*)(Ab + (size_t)raj[j] * Kp + k0 + oswaj[j]),
                (__attribute__((address_space(3))) void*)(sA + raj[j] * 64 + oaj[j]), 16, 0, 0);
#pragma unroll
        for (int j = 0; j < 4; ++j)
            __builtin_amdgcn_global_load_lds(
                (const __attribute__((address_space(1))) void*)(Bb + (size_t)rbj[j] * Kp + k0 + oswbj[j]),
                (__attribute__((address_space(3))) void*)(sB + rbj[j] * 64 + obj[j]), 16, 0, 0);
        __syncthreads();

#pragma unroll
        for (int ks = 0; ks < 64; ks += 32) {
            bf16x8 af[4], bfr[4];
#pragma unroll
            for (int i = 0; i < 4; ++i)
                af[i] = *(const bf16x8*)(sA + (arow + i * 16) * 64 + ((ks + koff) ^ aswz));
#pragma unroll
            for (int i = 0; i < 4; ++i)
                bfr[i] = *(const bf16x8*)(sB + (brow + i * 16) * 64 + ((ks + koff) ^ bswz));
#pragma unroll
            for (int mi = 0; mi < 4; ++mi)
#pragma unroll
                for (int ni = 0; ni < 4; ++ni)
                    acc[mi][ni] = __builtin_amdgcn_mfma_f32_16x16x32_bf16(
                        af[mi], bfr[ni], acc[mi][ni], 0, 0, 0);
        }
        __syncthreads();
    }

    int crow0 = rowbase + wm + (lane >> 4) * 4;
    int ccol0 = colbase + wn + (lane & 15);
#pragma unroll
    for (int mi = 0; mi < 4; ++mi) {
#pragma unroll
        for (int r = 0; r < 4; ++r) {
            int row = crow0 + mi * 16 + r;
            if (row < NNODES) {
#pragma unroll
                for (int ni = 0; ni < 4; ++ni)
                    C[(size_t)row * m + ccol0 + ni * 16] = f2bf(acc[mi][ni][r]);
            }
        }
    }
}

// -------------- attention scalars: one wave per node, coalesced --------------
template <int DOUT>
__global__ __launch_bounds__(256)
void att_scalar_v2(const unsigned short* __restrict__ Wx, const float* __restrict__ a,
                   float* __restrict__ asrc, float* __restrict__ adst) {
    constexpr int HD = DOUT / HEADS;   // 64 or 128
    constexpr int PER = DOUT / 64;     // 4 or 8
    __shared__ float sa[2 * HD];
    int tid = threadIdx.x;
    if (tid < 2 * HD) sa[tid] = a[tid];
    __syncthreads();

    int wave = tid >> 6, lane = tid & 63;
    int node = blockIdx.x * 4 + wave;
    if (node >= NNODES) return;

    int j = lane * PER;
    int h = lane >> 4;                 // head (both DOUT cases)
    int dl = (lane & 15) * PER;        // local d within head
    const unsigned short* base = Wx + (size_t)node * DOUT + j;

    float s1 = 0.f, s2 = 0.f;
#pragma unroll
    for (int t = 0; t < PER; t += 4) {
        u16x4 v4 = *(const u16x4*)(base + t);
#pragma unroll
        for (int q = 0; q < 4; ++q) {
            float v = bf2f(v4[q]);
            s1 = fmaf(v, sa[dl + t + q], s1);
            s2 = fmaf(v, sa[HD + dl + t + q], s2);
        }
    }
    // reduce within 16-lane head groups
#pragma unroll
    for (int off = 1; off < 16; off <<= 1) {
        s1 += __shfl_xor(s1, off);
        s2 += __shfl_xor(s2, off);
    }
    if ((lane & 15) == 0) {
        asrc[node * HEADS + h] = s1;
        adst[node * HEADS + h] = s2;
    }
}

// -------------- fused gather-aggregate + softmax + ELU + LayerNorm -----------
// One wave per node. Lane owns PER contiguous outputs; head h = lane>>4.
// Denominator folded: out = (sum_e exp_e * Wx_src) / (sum_e exp_e + 1e-8).
template <int DOUT, bool OUT_BF>
__global__ __launch_bounds__(256)
void aggregate_wave(const int* __restrict__ rowptr, const int* __restrict__ srcs,
                    const float* __restrict__ asrc, const float* __restrict__ adst,
                    const unsigned short* __restrict__ WxB,
                    const float* __restrict__ g, const float* __restrict__ b,
                    void* __restrict__ outp) {
    constexpr int PER = DOUT / 64;     // 4 (DOUT=256) or 8 (DOUT=512)
    int wid = threadIdx.x >> 6, lane = threadIdx.x & 63;
    int node = blockIdx.x * 4 + wid;
    if (node >= NNODES) return;

    int h = lane >> 4;                 // head for this lane's output slice
    int li = lane & 15;
    int hb = lane & 48;                // shfl base for this head group
    int beg = rowptr[node], end = rowptr[node + 1];
    float adh = adst[node * HEADS + h];

    const unsigned short* wb = WxB + lane * PER;

    float acc[PER];
#pragma unroll
    for (int q = 0; q < PER; ++q) acc[q] = 0.f;
    float dloc = 0.f;

    typedef __attribute__((ext_vector_type(PER))) unsigned short uvec;

    for (int cb = beg; cb < end; cb += 16) {
        int cnt = min(16, end - cb);
        int s = 0;
        float ex = 0.f;
        if (li < cnt) {
            s = srcs[cb + li];
            float e = asrc[s * HEADS + h] + adh;
            e = e > 0.f ? e : 0.2f * e;
            ex = __expf(e);
        }
        dloc += ex;
        int i = 0;
        for (; i + 4 <= cnt; i += 4) {
            int s0 = __builtin_amdgcn_readlane(s, i);
            int s1 = __builtin_amdgcn_readlane(s, i + 1);
            int s2 = __builtin_amdgcn_readlane(s, i + 2);
            int s3 = __builtin_amdgcn_readlane(s, i + 3);
            uvec v0 = *(const uvec*)(wb + (size_t)s0 * DOUT);
            uvec v1 = *(const uvec*)(wb + (size_t)s1 * DOUT);
            uvec v2 = *(const uvec*)(wb + (size_t)s2 * DOUT);
            uvec v3 = *(const uvec*)(wb + (size_t)s3 * DOUT);
            float w0 = __shfl(ex, hb | i);
            float w1 = __shfl(ex, hb | (i + 1));
            float w2 = __shfl(ex, hb | (i + 2));
            float w3 = __shfl(ex, hb | (i + 3));
#pragma unroll
            for (int q = 0; q < PER; ++q) {
                float t0 = fmaf(w0, bf2f(v0[q]), acc[q]);
                float t1 = fmaf(w1, bf2f(v1[q]), t0);
                float t2 = fmaf(w2, bf2f(v2[q]), t1);
                acc[q] = fmaf(w3, bf2f(v3[q]), t2);
            }
        }
        for (; i < cnt; ++i) {
            int si = __builtin_amdgcn_readlane(s, i);
            uvec v = *(const uvec*)(wb + (size_t)si * DOUT);
            float w = __shfl(ex, hb | i);
#pragma unroll
            for (int q = 0; q < PER; ++q)
                acc[q] = fmaf(w, bf2f(v[q]), acc[q]);
        }
    }

    // reduce per-head denominator across the 16-lane group
    float dsum = dloc;
#pragma unroll
    for (int off = 1; off < 16; off <<= 1) dsum += __shfl_xor(dsum, off);

    float rd = 1.f / (dsum + 1e-8f);
    float vals[PER];
    float lsum = 0.f, lsq = 0.f;
#pragma unroll
    for (int q = 0; q < PER; ++q) {
        float v = acc[q] * rd;
        v = v > 0.f ? v : __expf(v) - 1.f;   // ELU
        vals[q] = v;
        lsum += v;
        lsq = fmaf(v, v, lsq);
    }
#pragma unroll
    for (int off = 1; off < 64; off <<= 1) {
        lsum += __shfl_xor(lsum, off);
        lsq += __shfl_xor(lsq, off);
    }
    float mean = lsum * (1.0f / DOUT);
    float var = lsq * (1.0f / DOUT) - mean * mean;
    float rstd = rsqrtf(var + 1e-5f);

    int j = lane * PER;
    f32x4 g0 = *(const f32x4*)(g + j);
    f32x4 b0 = *(const f32x4*)(b + j);
    float r[PER];
#pragma unroll
    for (int q = 0; q < 4; ++q) r[q] = (vals[q] - mean) * rstd * g0[q] + b0[q];
    if constexpr (PER == 8) {
        f32x4 g1 = *(const f32x4*)(g + j + 4);
        f32x4 b1 = *(const f32x4*)(b + j + 4);
#pragma unroll
        for (int q = 0; q < 4; ++q)
            r[q + 4] = (vals[q + 4] - mean) * rstd * g1[q] + b1[q];
    }

    if constexpr (OUT_BF) {
        unsigned short* o = (unsigned short*)outp + (size_t)node * DOUT + j;
        u16x4 o0;
#pragma unroll
        for (int q = 0; q < 4; ++q) o0[q] = f2bf(r[q]);
        *(u16x4*)o = o0;
        if constexpr (PER == 8) {
            u16x4 o1;
#pragma unroll
            for (int q = 0; q < 4; ++q) o1[q] = f2bf(r[q + 4]);
            *(u16x4*)(o + 4) = o1;
        }
    } else {
        float* o = (float*)outp + (size_t)node * DOUT + j;
        f32x4 v0 = {r[0], r[1], r[2], r[3]};
        *(f32x4*)o = v0;
        if constexpr (PER == 8) {
            f32x4 v1 = {r[4], r[5], r[6], r[7]};
            *(f32x4*)(o + 4) = v1;
        }
    }
}

extern "C" void kernel_launch(void* const* d_in, const int* in_sizes, int n_in,
                              void* d_out, int out_size, void* d_ws, size_t ws_size,
                              hipStream_t stream) {
    const float* x0 = (const float*)d_in[0];
    const int* ei = (const int*)d_in[1];
    const int* src = ei;
    const int* dst = ei + NEDGES;
    const float* W[3]  = {(const float*)d_in[2], (const float*)d_in[6],  (const float*)d_in[10]};
    const float* a[3]  = {(const float*)d_in[3], (const float*)d_in[7],  (const float*)d_in[11]};
    const float* g[3]  = {(const float*)d_in[4], (const float*)d_in[8],  (const float*)d_in[12]};
    const float* bb[3] = {(const float*)d_in[5], (const float*)d_in[9],  (const float*)d_in[13]};

    char* p = (char*)d_ws;
    auto carve = [&](size_t bytes) {
        char* r = p;
        p += (bytes + 255) & ~(size_t)255;
        return r;
    };
    unsigned short* XB   = (unsigned short*)carve((size_t)NPAD * KP0 * 2);
    unsigned short* WxB  = (unsigned short*)carve((size_t)NNODES * 512 * 2);
    unsigned short* Wt0  = (unsigned short*)carve((size_t)256 * KP0 * 2);
    unsigned short* Wt1  = (unsigned short*)carve((size_t)256 * 256 * 2);
    unsigned short* Wt2  = (unsigned short*)carve((size_t)512 * 256 * 2);
    float* ASRC  = (float*)carve((size_t)NNODES * HEADS * 4);
    float* ADST  = (float*)carve((size_t)NNODES * HEADS * 4);
    int* CNT  = (int*)carve((size_t)NNODES * 4);
    int* ROWP = (int*)carve((size_t)(NNODES + 1) * 4);
    int* CURS = (int*)carve((size_t)NNODES * 4);
    int* SRCS = (int*)carve((size_t)NEDGES * 4);
    int* BSUM = (int*)carve(256 * 4);
    int* BOFF = (int*)carve(256 * 4);
    unsigned short* Wt[3] = {Wt0, Wt1, Wt2};

    // independent prep: CSR build + input/weight conversion
    hipMemsetAsync(CNT, 0, (size_t)NNODES * 4, stream);
    count_deg<<<(NEDGES + 255) / 256, 256, 0, stream>>>(dst, CNT);
    scan_p1<<<NSCAN_BLK, 256, 0, stream>>>(CNT, BSUM);
    scan_p2<<<1, 256, 0, stream>>>(BSUM, BOFF, ROWP);
    scan_p3<<<NSCAN_BLK, 256, 0, stream>>>(CNT, BOFF, ROWP, CURS);
    fill_csr<<<(NEDGES + 255) / 256, 256, 0, stream>>>(src, dst, CURS, SRCS);
    conv_x_v2<<<((size_t)NNODES * TPR + 255) / 256, 256, 0, stream>>>(x0, XB);
    conv_wt_all<<<(SEG0 + SEG1 + SEG2 + 255) / 256, 256, 0, stream>>>(
        W[0], W[1], W[2], Wt0, Wt1, Wt2);

    const int dims[4] = {523, 256, 256, 512};
    const int Kps[3] = {KP0, 256, 256};
    for (int li = 0; li < 3; ++li) {
        int dout = dims[li + 1];
        int Kp = Kps[li];

        int nblk = (dout == 256) ? (NPAD / 128) : 2 * (NPAD / 128);
        gemm_mfma<<<nblk, 512, 0, stream>>>(XB, Wt[li], WxB, Kp, dout);

        if (dout == 256)
            att_scalar_v2<256><<<(NNODES + 3) / 4, 256, 0, stream>>>(WxB, a[li], ASRC, ADST);
        else
            att_scalar_v2<512><<<(NNODES + 3) / 4, 256, 0, stream>>>(WxB, a[li], ASRC, ADST);

        if (li == 2) {
            aggregate_wave<512, false><<<(NNODES + 3) / 4, 256, 0, stream>>>(
                ROWP, SRCS, ASRC, ADST, WxB, g[li], bb[li], d_out);
        } else {
            aggregate_wave<256, true><<<(NNODES + 3) / 4, 256, 0, stream>>>(
                ROWP, SRCS, ASRC, ADST, WxB, g[li], bb[li], (void*)XB);
        }
    }
}